// Round 4
// baseline (197.240 us; speedup 1.0000x reference)
//
#include <hip/hip_runtime.h>
#include <hip/hip_bf16.h>

#define T_TOK 8192
#define DIN   4096
#define DOUT  4096
#define RANK  64
#define NAD   8
#define TS    32          // tokens per tile
#define MAXTILES 264      // sum ceil(count_a/TS) <= 256+7
#define TOTR  (NAD*RANK)  // 512
#define KSPLIT 4
#define KCH   (DIN / KSPLIT)   // 1024
#define NT    (KCH / 64)       // 16 K-steps of BK=64

typedef __bf16 bf16x8 __attribute__((ext_vector_type(8)));
typedef __bf16 bf16x4 __attribute__((ext_vector_type(4)));
typedef float  f32x4  __attribute__((ext_vector_type(4)));

// ---- workspace layout (bytes) ----
#define WS_CURSORS 0         // 8 int
#define WS_NTILES  64        // 1 int
#define WS_FLAG    128       // 1 int (ids are int64?)
#define WS_TINFO   256       // MAXTILES*3 int
#define WS_PERM    4096      // 8192 int
#define WS_XA      0x10000   // 8192*64 bf16 (1 MB)
#define WS_ABF     0x110000  // 512*4096 bf16 (4 MB)
#define WS_BT      0x510000  // 4096*512 bf16 (4 MB)
#define WS_XAP     0x910000  // KSPLIT*8192*64 fp32 (8 MB)
#define WS_END     (0x910000 + (size_t)KSPLIT * T_TOK * RANK * 4)

__device__ __forceinline__ void gll16(const void* g, void* l) {
  __builtin_amdgcn_global_load_lds(
      (const __attribute__((address_space(1))) unsigned int*)g,
      (__attribute__((address_space(3))) unsigned int*)l, 16, 0, 0);
}

// ---------------- prep: histogram + offsets + tile table ----------------
__global__ __launch_bounds__(1024) void hist_prep(const int* __restrict__ ids,
    int* __restrict__ cursors, int* __restrict__ ntilesp,
    int* __restrict__ flagp, int* __restrict__ tinfo) {
  __shared__ int cnt[NAD];
  __shared__ int s_is64;
  int tid = threadIdx.x, lane = tid & 63;
  if (tid < NAD) cnt[tid] = 0;
  if (tid == 0) s_is64 = 1;
  __syncthreads();
  // int64 detection: values are 0..7, so if data is i64 every odd 32-bit word is 0
  int any = 0;
  for (int i = tid; i < T_TOK; i += 1024)
    if (i & 1) any |= ids[i];
  if (any) s_is64 = 0;
  __syncthreads();
  int is64 = s_is64;
  int loc[NAD];
#pragma unroll
  for (int a = 0; a < NAD; ++a) loc[a] = 0;
  for (int t = tid; t < T_TOK; t += 1024) {
    int id = (is64 ? ids[2 * t] : ids[t]) & 7;
#pragma unroll
    for (int a = 0; a < NAD; ++a) {
      unsigned long long m = __ballot(id == a);
      if (lane == 0) loc[a] += __popcll(m);
    }
  }
  if (lane == 0) {
#pragma unroll
    for (int a = 0; a < NAD; ++a) if (loc[a]) atomicAdd(&cnt[a], loc[a]);
  }
  __syncthreads();
  if (tid == 0) {
    *flagp = is64;
    int ofs = 0, nt = 0;
    for (int a = 0; a < NAD; ++a) {
      int c = cnt[a];
      cursors[a] = ofs;
      for (int t0 = 0; t0 < c; t0 += TS) {
        tinfo[nt * 3 + 0] = a;
        tinfo[nt * 3 + 1] = ofs + t0;
        tinfo[nt * 3 + 2] = (c - t0 < TS) ? (c - t0) : TS;
        ++nt;
      }
      ofs += c;
    }
    *ntilesp = nt;
  }
}

// ---------------- scatter tokens into per-adapter groups ----------------
__global__ __launch_bounds__(512) void scatter_k(const int* __restrict__ ids,
    const int* __restrict__ flagp, int* __restrict__ cursors, int* __restrict__ perm) {
  int t = blockIdx.x * 512 + threadIdx.x;
  int id = ((*flagp) ? ids[2 * t] : ids[t]) & 7;
  int pos = atomicAdd(&cursors[id], 1);
  perm[pos] = t;
}

// ---------------- A fp32 -> bf16 (row major) ----------------
__global__ __launch_bounds__(256) void conv_a(const float* __restrict__ A,
                                              __bf16* __restrict__ Abf) {
  int i = blockIdx.x * 256 + threadIdx.x;          // TOTR*DIN/4 elements
  float4 v = ((const float4*)A)[i];
  bf16x4 o = { (__bf16)v.x, (__bf16)v.y, (__bf16)v.z, (__bf16)v.w };
  ((bf16x4*)Abf)[i] = o;
}

// ---------------- B fp32 [512][4096] -> Bt bf16 [4096][512] ----------------
__global__ __launch_bounds__(256) void trans_b(const float* __restrict__ B,
                                               __bf16* __restrict__ Bt) {
  __shared__ float t[64][65];
  int rb = blockIdx.x, db = blockIdx.y;
  int tid = threadIdx.x;
  int c = tid & 63, q = tid >> 6;                  // q: 0..3
#pragma unroll
  for (int i = 0; i < 16; ++i) {
    int r = i * 4 + q;
    t[r][c] = B[(size_t)(rb * 64 + r) * DOUT + db * 64 + c];
  }
  __syncthreads();
#pragma unroll
  for (int i = 0; i < 16; ++i) {
    int d = i * 4 + q;
    Bt[(size_t)(db * 64 + d) * TOTR + rb * 64 + c] = (__bf16)t[c][d];
  }
}

#define CVT8(lo, hi) { (__bf16)lo.x, (__bf16)lo.y, (__bf16)lo.z, (__bf16)lo.w, \
                       (__bf16)hi.x, (__bf16)hi.y, (__bf16)hi.z, (__bf16)hi.w }

// ---------------- stage 1 (split-K, LDS-staged): xap[ks][tok][rank] = X * A_a^T ----------------
__global__ __launch_bounds__(512) void stage1s(const float* __restrict__ x,
    const __bf16* __restrict__ Abf, const int* __restrict__ tinfo,
    const int* __restrict__ ntilesp, const int* __restrict__ perm,
    float* __restrict__ xap) {
  __shared__ char lds[2][16384];   // per buf: [0,8192) = x tile, [8192,16384) = A tile
  int b = blockIdx.x;
  if (b >= *ntilesp) return;       // uniform
  int ks = blockIdx.y;
  int a = tinfo[b * 3], start = tinfo[b * 3 + 1], nv = tinfo[b * 3 + 2];
  int tid = threadIdx.x, lane = tid & 63, wv = tid >> 6;

  // ---- staging addresses (constant across K-steps) ----
  int xr = wv * 4 + (lane >> 4);                       // x row this lane stages
  int xtok = (xr < nv) ? perm[start + xr] : perm[start];
  int xinner = ((lane & 15) * 16) ^ ((xr & 7) << 4);   // swizzled source inner bytes
  const char* xsrc = (const char*)(x + (size_t)xtok * DIN + ks * KCH) + xinner;
  int ar = wv * 8 + (lane >> 3);                       // A row this lane stages
  int ainner = ((lane & 7) * 16) ^ ((ar & 7) << 4);
  const char* asrc = (const char*)(Abf + (size_t)(a * RANK + ar) * DIN + ks * KCH) + ainner;

  // ---- compute-side indices ----
  int l16 = lane & 15, lq = lane >> 4;
  int rb = wv & 1, cb = wv >> 1;
  int xrow = rb * 16 + l16;        // token row (MFMA A-operand)
  int arow = cb * 16 + l16;        // rank row  (MFMA B-operand)
  int swx = (xrow & 7) << 4;
  int swa = (arow & 7) << 4;

  f32x4 acc = {0.f, 0.f, 0.f, 0.f};

  // prologue: stage K-step 0 into buf 0
  gll16(xsrc, &lds[0][wv * 1024]);
  gll16(asrc, &lds[0][8192 + wv * 1024]);

  for (int t = 0; t < NT; ++t) {
    const char* cbuf = lds[t & 1];
    if (t + 1 < NT) {
      char* nbuf = lds[(t + 1) & 1];
      gll16(xsrc + (size_t)(t + 1) * 256, nbuf + wv * 1024);
      gll16(asrc + (size_t)(t + 1) * 128, nbuf + 8192 + wv * 1024);
      asm volatile("s_waitcnt vmcnt(2)" ::: "memory");   // cur's 2 loads landed
    } else {
      asm volatile("s_waitcnt vmcnt(0)" ::: "memory");
    }
    __builtin_amdgcn_s_barrier();
    asm volatile("" ::: "memory");
#pragma unroll
    for (int m = 0; m < 2; ++m) {
      f32x4 xv0 = *(const f32x4*)(cbuf + xrow * 256 + ((m * 128 + lq * 32) ^ swx));
      f32x4 xv1 = *(const f32x4*)(cbuf + xrow * 256 + ((m * 128 + lq * 32 + 16) ^ swx));
      bf16x8 xf = { (__bf16)xv0[0], (__bf16)xv0[1], (__bf16)xv0[2], (__bf16)xv0[3],
                    (__bf16)xv1[0], (__bf16)xv1[1], (__bf16)xv1[2], (__bf16)xv1[3] };
      bf16x8 af = *(const bf16x8*)(cbuf + 8192 + arow * 128 + ((m * 64 + lq * 16) ^ swa));
      acc = __builtin_amdgcn_mfma_f32_16x16x32_bf16(xf, af, acc, 0, 0, 0);
    }
    asm volatile("" ::: "memory");
    __builtin_amdgcn_s_barrier();
  }

  float* xo = xap + (size_t)ks * T_TOK * RANK;
#pragma unroll
  for (int j = 0; j < 4; ++j) {
    int tr = rb * 16 + lq * 4 + j;
    if (tr < nv) {
      int tk = perm[start + tr];
      xo[(size_t)tk * RANK + cb * 16 + l16] = acc[j];
    }
  }
}

// ---------------- reduce partials -> bf16 xa ----------------
__global__ __launch_bounds__(256) void reduce_xa(const float* __restrict__ xap,
                                                 __bf16* __restrict__ xa) {
  int i = blockIdx.x * 256 + threadIdx.x;          // 131072 float4 groups
  const float4* p = (const float4*)xap;
  float4 s = p[i];
#pragma unroll
  for (int ks = 1; ks < KSPLIT; ++ks) {
    float4 q = p[(size_t)ks * (T_TOK * RANK / 4) + i];
    s.x += q.x; s.y += q.y; s.z += q.z; s.w += q.w;
  }
  bf16x4 o = { (__bf16)s.x, (__bf16)s.y, (__bf16)s.z, (__bf16)s.w };
  ((bf16x4*)xa)[i] = o;
}

// ---------------- stage 1 fallback (no split-K) — used only if ws too small ----------------
__global__ __launch_bounds__(512) void stage1f(const float* __restrict__ x,
    const __bf16* __restrict__ Abf, const int* __restrict__ tinfo,
    const int* __restrict__ ntilesp, const int* __restrict__ perm,
    __bf16* __restrict__ xa) {
  int b = blockIdx.x;
  if (b >= *ntilesp) return;
  int a = tinfo[b * 3], start = tinfo[b * 3 + 1], nv = tinfo[b * 3 + 2];
  int tid = threadIdx.x, lane = tid & 63, w = tid >> 6;
  int rb = w & 1, cb = w >> 1;
  int l16 = lane & 15, lq = lane >> 4;
  int trow = rb * 16 + l16;
  int tok = (trow < nv) ? perm[start + trow] : 0;
  const float*  xrow = x + (size_t)tok * DIN + lq * 8;
  const __bf16* arow = Abf + (size_t)(a * RANK + cb * 16 + l16) * DIN + lq * 8;
  f32x4 acc = {0.f, 0.f, 0.f, 0.f};
#pragma unroll 4
  for (int k0 = 0; k0 < DIN; k0 += 32) {
    float4 v0 = *(const float4*)(xrow + k0);
    float4 v1 = *(const float4*)(xrow + k0 + 4);
    bf16x8 af = CVT8(v0, v1);
    bf16x8 bfr = *(const bf16x8*)(arow + k0);
    acc = __builtin_amdgcn_mfma_f32_16x16x32_bf16(af, bfr, acc, 0, 0, 0);
  }
#pragma unroll
  for (int j = 0; j < 4; ++j) {
    int tr = rb * 16 + lq * 4 + j;
    if (tr < nv) {
      int tk = perm[start + tr];
      xa[(size_t)tk * RANK + cb * 16 + l16] = (__bf16)acc[j];
    }
  }
}

// ---------------- stage 2 (swapped-operand): out[32 tok][256 d] = base + 2 * xa * B_a ----------------
// grid (DOUT/256, MAXTILES), block 512 (8 waves): wave -> token half (w&1), 64-d group (w>>1).
// MFMA computed as mfma(Bt_frag, xa_frag, acc): M=d, N=token. C layout then gives each lane
// ONE token (col=l16) and 4 CONSECUTIVE d (row=lq*4+j) -> float4 base loads + float4 stores.
__global__ __launch_bounds__(512, 4) void stage2(const __bf16* __restrict__ xa,
    const __bf16* __restrict__ Bt, const float* __restrict__ base,
    const int* __restrict__ tinfo, const int* __restrict__ ntilesp,
    const int* __restrict__ perm, float* __restrict__ out) {
  int b = blockIdx.y;
  if (b >= *ntilesp) return;
  int a = tinfo[b * 3], start = tinfo[b * 3 + 1], nv = tinfo[b * 3 + 2];
  int tid = threadIdx.x, lane = tid & 63, w = tid >> 6;
  int tb = w & 1, dg = w >> 1;
  int l16 = lane & 15, lq = lane >> 4;

  // each lane owns one token (the MFMA N column l16)
  int tr = tb * 16 + l16;
  bool valid = (tr < nv);
  int token = valid ? perm[start + tr] : perm[start];

  // xa fragment (B-operand): xa[token][k], k = lq*8 (+32 for second MFMA)
  const __bf16* xrow = xa + (size_t)token * RANK + lq * 8;
  bf16x8 xv0 = *(const bf16x8*)(xrow);
  bf16x8 xv1 = *(const bf16x8*)(xrow + 32);

  int dwave = blockIdx.x * 256 + dg * 64;          // this wave's 64-d span

  // Bt fragments (A-operand): row = d = dtile + l16, k = lq*8 (+32)
  bf16x8 bt0[4], bt1[4];
#pragma unroll
  for (int dt = 0; dt < 4; ++dt) {
    const __bf16* brow = Bt + (size_t)(dwave + dt * 16 + l16) * TOTR + a * RANK + lq * 8;
    bt0[dt] = *(const bf16x8*)(brow);
    bt1[dt] = *(const bf16x8*)(brow + 32);
  }

  // base loads: float4 at [token][dtile + lq*4]
  const float* brow_base = base + (size_t)token * DOUT + dwave + lq * 4;
  float4 bs[4];
#pragma unroll
  for (int dt = 0; dt < 4; ++dt)
    bs[dt] = *(const float4*)(brow_base + dt * 16);

  f32x4 acc[4];
#pragma unroll
  for (int dt = 0; dt < 4; ++dt) {
    f32x4 z = {0.f, 0.f, 0.f, 0.f};
    z = __builtin_amdgcn_mfma_f32_16x16x32_bf16(bt0[dt], xv0, z, 0, 0, 0);
    z = __builtin_amdgcn_mfma_f32_16x16x32_bf16(bt1[dt], xv1, z, 0, 0, 0);
    acc[dt] = z;
  }

  if (valid) {
    float* orow = out + (size_t)token * DOUT + dwave + lq * 4;
#pragma unroll
    for (int dt = 0; dt < 4; ++dt) {
      float4 o = { bs[dt].x + 2.0f * acc[dt][0],
                   bs[dt].y + 2.0f * acc[dt][1],
                   bs[dt].z + 2.0f * acc[dt][2],
                   bs[dt].w + 2.0f * acc[dt][3] };
      *(float4*)(orow + dt * 16) = o;
    }
  }
}

extern "C" void kernel_launch(void* const* d_in, const int* in_sizes, int n_in,
                              void* d_out, int out_size, void* d_ws, size_t ws_size,
                              hipStream_t stream) {
  const float* x   = (const float*)d_in[0];
  const float* A   = (const float*)d_in[1];
  const float* B   = (const float*)d_in[2];
  const float* bas = (const float*)d_in[3];
  const int*   ids = (const int*)d_in[4];
  float* out = (float*)d_out;
  char* ws = (char*)d_ws;
  int* cursors = (int*)(ws + WS_CURSORS);
  int* ntiles  = (int*)(ws + WS_NTILES);
  int* flag    = (int*)(ws + WS_FLAG);
  int* tinfo   = (int*)(ws + WS_TINFO);
  int* perm    = (int*)(ws + WS_PERM);
  __bf16* xa   = (__bf16*)(ws + WS_XA);
  __bf16* Abf  = (__bf16*)(ws + WS_ABF);
  __bf16* Bt   = (__bf16*)(ws + WS_BT);
  float*  xap  = (float*)(ws + WS_XAP);

  hist_prep<<<1, 1024, 0, stream>>>(ids, cursors, ntiles, flag, tinfo);
  scatter_k<<<T_TOK / 512, 512, 0, stream>>>(ids, flag, cursors, perm);
  conv_a<<<(TOTR * DIN / 4) / 256, 256, 0, stream>>>(A, Abf);
  trans_b<<<dim3(TOTR / 64, DOUT / 64), 256, 0, stream>>>(B, Bt);
  if (ws_size >= WS_END) {
    stage1s<<<dim3(MAXTILES, KSPLIT), 512, 0, stream>>>(x, Abf, tinfo, ntiles, perm, xap);
    reduce_xa<<<(T_TOK * RANK / 4) / 256, 256, 0, stream>>>(xap, xa);
  } else {
    stage1f<<<MAXTILES, 512, 0, stream>>>(x, Abf, tinfo, ntiles, perm, xa);
  }
  stage2<<<dim3(DOUT / 256, MAXTILES), 512, 0, stream>>>(xa, Bt, bas, tinfo, ntiles, perm, out);
}

// Round 5
// 150.312 us; speedup vs baseline: 1.3122x; 1.3122x over previous
//
#include <hip/hip_runtime.h>
#include <hip/hip_bf16.h>

#define T_TOK 8192
#define DIN   4096
#define DOUT  4096
#define RANK  64
#define NAD   8
#define TS    32          // tokens per tile
#define MAXTILES 264      // sum ceil(count_a/TS) <= 256+7
#define TOTR  (NAD*RANK)  // 512
#define KSPLIT 4
#define KCH   (DIN / KSPLIT)   // 1024
#define NT    (KCH / 64)       // 16 K-steps of BK=64
#define DSPLIT 8
#define DCH   (DOUT / DSPLIT)  // 512
#define NS    (DCH / 64)       // 8 d-steps of 64

typedef __bf16 bf16x8 __attribute__((ext_vector_type(8)));
typedef __bf16 bf16x4 __attribute__((ext_vector_type(4)));
typedef float  f32x4  __attribute__((ext_vector_type(4)));

// ---- workspace layout (bytes) ----
#define WS_CURSORS 0         // 8 int
#define WS_NTILES  64        // 1 int
#define WS_FLAG    128       // 1 int (ids are int64?)
#define WS_TINFO   256       // MAXTILES*3 int
#define WS_PERM    4096      // 8192 int
#define WS_XA      0x10000   // 8192*64 bf16 (1 MB)
#define WS_ABF     0x110000  // 512*4096 bf16 (4 MB)
#define WS_BT      0x510000  // 4096*512 bf16 (4 MB)
#define WS_XAP     0x910000  // KSPLIT*8192*64 fp32 (8 MB)
#define WS_END     (0x910000 + (size_t)KSPLIT * T_TOK * RANK * 4)

__device__ __forceinline__ void gll16(const void* g, void* l) {
  __builtin_amdgcn_global_load_lds(
      (const __attribute__((address_space(1))) unsigned int*)g,
      (__attribute__((address_space(3))) unsigned int*)l, 16, 0, 0);
}

// ---------------- prep: histogram + offsets + tile table ----------------
__global__ __launch_bounds__(1024) void hist_prep(const int* __restrict__ ids,
    int* __restrict__ cursors, int* __restrict__ ntilesp,
    int* __restrict__ flagp, int* __restrict__ tinfo) {
  __shared__ int cnt[NAD];
  __shared__ int s_ofs[NAD], s_tbase[NAD + 1];
  __shared__ int s_is64;
  int tid = threadIdx.x, lane = tid & 63;
  if (tid < NAD) cnt[tid] = 0;
  if (tid == 0) s_is64 = 1;
  __syncthreads();
  // int64 detection: values are 0..7, so if data is i64 every odd 32-bit word is 0
  int any = 0;
  for (int i = tid; i < T_TOK; i += 1024)
    if (i & 1) any |= ids[i];
  if (any) s_is64 = 0;
  __syncthreads();
  int is64 = s_is64;
  int loc[NAD];
#pragma unroll
  for (int a = 0; a < NAD; ++a) loc[a] = 0;
  for (int t = tid; t < T_TOK; t += 1024) {
    int id = (is64 ? ids[2 * t] : ids[t]) & 7;
#pragma unroll
    for (int a = 0; a < NAD; ++a) {
      unsigned long long m = __ballot(id == a);
      if (lane == 0) loc[a] += __popcll(m);
    }
  }
  if (lane == 0) {
#pragma unroll
    for (int a = 0; a < NAD; ++a) if (loc[a]) atomicAdd(&cnt[a], loc[a]);
  }
  __syncthreads();
  if (tid == 0) {
    *flagp = is64;
    int ofs = 0, tb = 0;
    for (int a = 0; a < NAD; ++a) {
      s_ofs[a] = ofs; cursors[a] = ofs;
      s_tbase[a] = tb;
      ofs += cnt[a];
      tb += (cnt[a] + TS - 1) / TS;
    }
    s_tbase[NAD] = tb;
    *ntilesp = tb;
  }
  __syncthreads();
  int ntt = s_tbase[NAD];
  for (int e = tid; e < ntt; e += 1024) {
    int a = 0;
    while (e >= s_tbase[a + 1]) ++a;
    int t0 = (e - s_tbase[a]) * TS;
    int c = cnt[a];
    tinfo[e * 3 + 0] = a;
    tinfo[e * 3 + 1] = s_ofs[a] + t0;
    tinfo[e * 3 + 2] = (c - t0 < TS) ? (c - t0) : TS;
  }
}

// ---------------- scatter tokens into per-adapter groups (wave-aggregated atomics) ----------------
__global__ __launch_bounds__(256) void scatter_k(const int* __restrict__ ids,
    const int* __restrict__ flagp, int* __restrict__ cursors, int* __restrict__ perm) {
  int t = blockIdx.x * 256 + threadIdx.x;
  int lane = threadIdx.x & 63;
  int id = ((*flagp) ? ids[2 * t] : ids[t]) & 7;
  unsigned long long lt = (1ull << lane) - 1ull;
#pragma unroll
  for (int a = 0; a < NAD; ++a) {
    unsigned long long m = __ballot(id == a);
    if (m) {
      int leader = __ffsll((long long)m) - 1;
      int base_a = 0;
      if (lane == leader) base_a = atomicAdd(&cursors[a], __popcll(m));
      base_a = __shfl(base_a, leader, 64);
      if (id == a) perm[base_a + __popcll(m & lt)] = t;
    }
  }
}

// ---------------- A fp32 -> bf16 (row major) ----------------
__global__ __launch_bounds__(256) void conv_a(const float* __restrict__ A,
                                              __bf16* __restrict__ Abf) {
  int i = blockIdx.x * 256 + threadIdx.x;          // TOTR*DIN/4 elements
  float4 v = ((const float4*)A)[i];
  bf16x4 o = { (__bf16)v.x, (__bf16)v.y, (__bf16)v.z, (__bf16)v.w };
  ((bf16x4*)Abf)[i] = o;
}

// ---------------- B fp32 [512][4096] -> Bt bf16 [4096][512] ----------------
__global__ __launch_bounds__(256) void trans_b(const float* __restrict__ B,
                                               __bf16* __restrict__ Bt) {
  __shared__ float t[64][65];
  int rb = blockIdx.x, db = blockIdx.y;
  int tid = threadIdx.x;
  int c = tid & 63, q = tid >> 6;                  // q: 0..3
#pragma unroll
  for (int i = 0; i < 16; ++i) {
    int r = i * 4 + q;
    t[r][c] = B[(size_t)(rb * 64 + r) * DOUT + db * 64 + c];
  }
  __syncthreads();
#pragma unroll
  for (int i = 0; i < 16; ++i) {
    int d = i * 4 + q;
    Bt[(size_t)(db * 64 + d) * TOTR + rb * 64 + c] = (__bf16)t[c][d];
  }
}

#define CVT8(lo, hi) { (__bf16)lo.x, (__bf16)lo.y, (__bf16)lo.z, (__bf16)lo.w, \
                       (__bf16)hi.x, (__bf16)hi.y, (__bf16)hi.z, (__bf16)hi.w }

// ---------------- stage 1 (split-K, LDS-staged): xap[ks][tok][rank] = X * A_a^T ----------------
__global__ __launch_bounds__(512) void stage1s(const float* __restrict__ x,
    const __bf16* __restrict__ Abf, const int* __restrict__ tinfo,
    const int* __restrict__ ntilesp, const int* __restrict__ perm,
    float* __restrict__ xap) {
  __shared__ char lds[2][16384];   // per buf: [0,8192) = x tile, [8192,16384) = A tile
  int b = blockIdx.x;
  if (b >= *ntilesp) return;       // uniform
  int ks = blockIdx.y;
  int a = tinfo[b * 3], start = tinfo[b * 3 + 1], nv = tinfo[b * 3 + 2];
  int tid = threadIdx.x, lane = tid & 63, wv = tid >> 6;

  // ---- staging addresses (constant across K-steps) ----
  int xr = wv * 4 + (lane >> 4);                       // x row this lane stages
  int xtok = (xr < nv) ? perm[start + xr] : perm[start];
  int xinner = ((lane & 15) * 16) ^ ((xr & 7) << 4);   // swizzled source inner bytes
  const char* xsrc = (const char*)(x + (size_t)xtok * DIN + ks * KCH) + xinner;
  int ar = wv * 8 + (lane >> 3);                       // A row this lane stages
  int ainner = ((lane & 7) * 16) ^ ((ar & 7) << 4);
  const char* asrc = (const char*)(Abf + (size_t)(a * RANK + ar) * DIN + ks * KCH) + ainner;

  // ---- compute-side indices ----
  int l16 = lane & 15, lq = lane >> 4;
  int rb = wv & 1, cb = wv >> 1;
  int xrow = rb * 16 + l16;        // token row (MFMA A-operand)
  int arow = cb * 16 + l16;        // rank row  (MFMA B-operand)
  int swx = (xrow & 7) << 4;
  int swa = (arow & 7) << 4;

  f32x4 acc = {0.f, 0.f, 0.f, 0.f};

  // prologue: stage K-step 0 into buf 0
  gll16(xsrc, &lds[0][wv * 1024]);
  gll16(asrc, &lds[0][8192 + wv * 1024]);

  for (int t = 0; t < NT; ++t) {
    const char* cbuf = lds[t & 1];
    if (t + 1 < NT) {
      char* nbuf = lds[(t + 1) & 1];
      gll16(xsrc + (size_t)(t + 1) * 256, nbuf + wv * 1024);
      gll16(asrc + (size_t)(t + 1) * 128, nbuf + 8192 + wv * 1024);
      asm volatile("s_waitcnt vmcnt(2)" ::: "memory");   // cur's 2 loads landed
    } else {
      asm volatile("s_waitcnt vmcnt(0)" ::: "memory");
    }
    __builtin_amdgcn_s_barrier();
    asm volatile("" ::: "memory");
#pragma unroll
    for (int m = 0; m < 2; ++m) {
      f32x4 xv0 = *(const f32x4*)(cbuf + xrow * 256 + ((m * 128 + lq * 32) ^ swx));
      f32x4 xv1 = *(const f32x4*)(cbuf + xrow * 256 + ((m * 128 + lq * 32 + 16) ^ swx));
      bf16x8 xf = { (__bf16)xv0[0], (__bf16)xv0[1], (__bf16)xv0[2], (__bf16)xv0[3],
                    (__bf16)xv1[0], (__bf16)xv1[1], (__bf16)xv1[2], (__bf16)xv1[3] };
      bf16x8 af = *(const bf16x8*)(cbuf + 8192 + arow * 128 + ((m * 64 + lq * 16) ^ swa));
      acc = __builtin_amdgcn_mfma_f32_16x16x32_bf16(xf, af, acc, 0, 0, 0);
    }
    asm volatile("" ::: "memory");
    __builtin_amdgcn_s_barrier();
  }

  float* xo = xap + (size_t)ks * T_TOK * RANK;
#pragma unroll
  for (int j = 0; j < 4; ++j) {
    int tr = rb * 16 + lq * 4 + j;
    if (tr < nv) {
      int tk = perm[start + tr];
      xo[(size_t)tk * RANK + cb * 16 + l16] = acc[j];
    }
  }
}

// ---------------- reduce partials -> bf16 xa ----------------
__global__ __launch_bounds__(256) void reduce_xa(const float* __restrict__ xap,
                                                 __bf16* __restrict__ xa) {
  int i = blockIdx.x * 256 + threadIdx.x;          // 131072 float4 groups
  const float4* p = (const float4*)xap;
  float4 s = p[i];
#pragma unroll
  for (int ks = 1; ks < KSPLIT; ++ks) {
    float4 q = p[(size_t)ks * (T_TOK * RANK / 4) + i];
    s.x += q.x; s.y += q.y; s.z += q.z; s.w += q.w;
  }
  bf16x4 o = { (__bf16)s.x, (__bf16)s.y, (__bf16)s.z, (__bf16)s.w };
  ((bf16x4*)xa)[i] = o;
}

// ---------------- stage 1 fallback (no split-K) — used only if ws too small ----------------
__global__ __launch_bounds__(512) void stage1f(const float* __restrict__ x,
    const __bf16* __restrict__ Abf, const int* __restrict__ tinfo,
    const int* __restrict__ ntilesp, const int* __restrict__ perm,
    __bf16* __restrict__ xa) {
  int b = blockIdx.x;
  if (b >= *ntilesp) return;
  int a = tinfo[b * 3], start = tinfo[b * 3 + 1], nv = tinfo[b * 3 + 2];
  int tid = threadIdx.x, lane = tid & 63, w = tid >> 6;
  int rb = w & 1, cb = w >> 1;
  int l16 = lane & 15, lq = lane >> 4;
  int trow = rb * 16 + l16;
  int tok = (trow < nv) ? perm[start + trow] : 0;
  const float*  xrow = x + (size_t)tok * DIN + lq * 8;
  const __bf16* arow = Abf + (size_t)(a * RANK + cb * 16 + l16) * DIN + lq * 8;
  f32x4 acc = {0.f, 0.f, 0.f, 0.f};
#pragma unroll 4
  for (int k0 = 0; k0 < DIN; k0 += 32) {
    float4 v0 = *(const float4*)(xrow + k0);
    float4 v1 = *(const float4*)(xrow + k0 + 4);
    bf16x8 af = CVT8(v0, v1);
    bf16x8 bfr = *(const bf16x8*)(arow + k0);
    acc = __builtin_amdgcn_mfma_f32_16x16x32_bf16(af, bfr, acc, 0, 0, 0);
  }
#pragma unroll
  for (int j = 0; j < 4; ++j) {
    int tr = rb * 16 + lq * 4 + j;
    if (tr < nv) {
      int tk = perm[start + tr];
      xa[(size_t)tk * RANK + cb * 16 + l16] = (__bf16)acc[j];
    }
  }
}

// ---------------- stage 2 (LDS-staged, pipelined): out[32 tok][512 d] = base + 2 * xa * B_a ----
// grid (DSPLIT, MAXTILES), block 512 (8 waves). NS=8 steps of 64 d.
// Per step: stage base-tile [32tok][64d] f32 (8KB) + Bt-tile [64d][64r] bf16 (8KB) via
// global_load_lds, double-buffered; counted vmcnt. Swapped-operand MFMA (M=d, N=token):
// lane owns 1 token x 4 consecutive d -> float4 store. Both tiles XOR-swizzled (both sides).
__global__ __launch_bounds__(512) void stage2(const __bf16* __restrict__ xa,
    const __bf16* __restrict__ Bt, const float* __restrict__ base,
    const int* __restrict__ tinfo, const int* __restrict__ ntilesp,
    const int* __restrict__ perm, float* __restrict__ out) {
  __shared__ char lds[2][16384];   // per buf: [0,8192) = base tile, [8192,16384) = Bt tile
  int b = blockIdx.y;
  if (b >= *ntilesp) return;       // uniform
  int a = tinfo[b * 3], start = tinfo[b * 3 + 1], nv = tinfo[b * 3 + 2];
  int tid = threadIdx.x, lane = tid & 63, wv = tid >> 6;
  int dblk = blockIdx.x * DCH;

  // ---- staging addresses (advance by step) ----
  int brow = wv * 4 + (lane >> 4);                     // base-tile token row 0..31
  int btok = (brow < nv) ? perm[start + brow] : perm[start];
  int binner = ((lane & 15) * 16) ^ ((brow & 7) << 4);
  const char* bsrc = (const char*)(base + (size_t)btok * DOUT + dblk) + binner;
  int trow = wv * 8 + (lane >> 3);                     // Bt-tile d row 0..63
  int tinner = ((lane & 7) * 16) ^ ((trow & 7) << 4);
  const char* tsrc = (const char*)(Bt + (size_t)(dblk + trow) * TOTR + a * RANK) + tinner;

  // ---- compute mapping: wave -> token half (wv&1), 16-d slice (wv>>1) ----
  int tb = wv & 1, dg = wv >> 1;
  int l16 = lane & 15, lq = lane >> 4;
  int tIdx = tb * 16 + l16;        // token index in tile (C col)
  bool valid = tIdx < nv;
  int token = valid ? perm[start + tIdx] : perm[start];

  // xa fragments (B-operand), fixed for whole block
  const __bf16* xrow = xa + (size_t)token * RANK + lq * 8;
  bf16x8 xv0 = *(const bf16x8*)(xrow);
  bf16x8 xv1 = *(const bf16x8*)(xrow + 32);

  float* orow = out + (size_t)token * DOUT + dblk + dg * 16 + lq * 4;

  // LDS read offsets (per-step constant)
  int btrow = dg * 16 + l16;                           // d row in Bt tile
  int btoff0 = btrow * 128 + ((lq * 16) ^ ((btrow & 7) << 4));
  int btoff1 = btrow * 128 + ((lq * 16 + 64) ^ ((btrow & 7) << 4));
  int bsoff  = tIdx * 256 + ((dg * 64 + lq * 16) ^ ((tIdx & 7) << 4));

  asm volatile("" ::: "memory");
  // prologue: stage step 0 into buf 0
  gll16(bsrc, &lds[0][wv * 1024]);
  gll16(tsrc, &lds[0][8192 + wv * 1024]);

  for (int t = 0; t < NS; ++t) {
    const char* cbuf = lds[t & 1];
    if (t + 1 < NS) {
      char* nbuf = lds[(t + 1) & 1];
      gll16(bsrc + (size_t)(t + 1) * 256,   nbuf + wv * 1024);          // +64 d = 256 B/row
      gll16(tsrc + (size_t)(t + 1) * 65536, nbuf + 8192 + wv * 1024);   // +64 rows * 1024 B
      asm volatile("s_waitcnt vmcnt(2)" ::: "memory");  // retires cur step's 2 stages (+old store)
    } else {
      asm volatile("s_waitcnt vmcnt(0)" ::: "memory");
    }
    __builtin_amdgcn_s_barrier();
    asm volatile("" ::: "memory");
    bf16x8 bf0 = *(const bf16x8*)(cbuf + 8192 + btoff0);
    bf16x8 bf1 = *(const bf16x8*)(cbuf + 8192 + btoff1);
    f32x4  bs  = *(const f32x4*)(cbuf + bsoff);
    f32x4 z = {0.f, 0.f, 0.f, 0.f};
    z = __builtin_amdgcn_mfma_f32_16x16x32_bf16(bf0, xv0, z, 0, 0, 0);
    z = __builtin_amdgcn_mfma_f32_16x16x32_bf16(bf1, xv1, z, 0, 0, 0);
    if (valid) {
      float4 o = { bs[0] + 2.0f * z[0], bs[1] + 2.0f * z[1],
                   bs[2] + 2.0f * z[2], bs[3] + 2.0f * z[3] };
      *(float4*)(orow + t * 64) = o;
    }
    asm volatile("" ::: "memory");
    __builtin_amdgcn_s_barrier();
  }
}

extern "C" void kernel_launch(void* const* d_in, const int* in_sizes, int n_in,
                              void* d_out, int out_size, void* d_ws, size_t ws_size,
                              hipStream_t stream) {
  const float* x   = (const float*)d_in[0];
  const float* A   = (const float*)d_in[1];
  const float* B   = (const float*)d_in[2];
  const float* bas = (const float*)d_in[3];
  const int*   ids = (const int*)d_in[4];
  float* out = (float*)d_out;
  char* ws = (char*)d_ws;
  int* cursors = (int*)(ws + WS_CURSORS);
  int* ntiles  = (int*)(ws + WS_NTILES);
  int* flag    = (int*)(ws + WS_FLAG);
  int* tinfo   = (int*)(ws + WS_TINFO);
  int* perm    = (int*)(ws + WS_PERM);
  __bf16* xa   = (__bf16*)(ws + WS_XA);
  __bf16* Abf  = (__bf16*)(ws + WS_ABF);
  __bf16* Bt   = (__bf16*)(ws + WS_BT);
  float*  xap  = (float*)(ws + WS_XAP);

  hist_prep<<<1, 1024, 0, stream>>>(ids, cursors, ntiles, flag, tinfo);
  scatter_k<<<T_TOK / 256, 256, 0, stream>>>(ids, flag, cursors, perm);
  conv_a<<<(TOTR * DIN / 4) / 256, 256, 0, stream>>>(A, Abf);
  trans_b<<<dim3(TOTR / 64, DOUT / 64), 256, 0, stream>>>(B, Bt);
  if (ws_size >= WS_END) {
    stage1s<<<dim3(MAXTILES, KSPLIT), 512, 0, stream>>>(x, Abf, tinfo, ntiles, perm, xap);
    reduce_xa<<<(T_TOK * RANK / 4) / 256, 256, 0, stream>>>(xap, xa);
  } else {
    stage1f<<<MAXTILES, 512, 0, stream>>>(x, Abf, tinfo, ntiles, perm, xa);
  }
  stage2<<<dim3(DSPLIT, MAXTILES), 512, 0, stream>>>(xa, Bt, bas, tinfo, ntiles, perm, out);
}

// Round 7
// 146.305 us; speedup vs baseline: 1.3481x; 1.0274x over previous
//
#include <hip/hip_runtime.h>
#include <hip/hip_bf16.h>

#define T_TOK 8192
#define DIN   4096
#define DOUT  4096
#define RANK  64
#define NAD   8
#define TS    32          // tokens per tile
#define MAXTILES 264      // sum ceil(count_a/TS) <= 256+7
#define TOTR  (NAD*RANK)  // 512
#define KSPLIT 4
#define KCH   (DIN / KSPLIT)   // 1024
#define NT    (KCH / 64)       // 16 K-steps of BK=64
#define DSPLIT 8
#define DCH   (DOUT / DSPLIT)  // 512
#define NS    (DCH / 64)       // 8 d-steps of 64

typedef __bf16 bf16x8 __attribute__((ext_vector_type(8)));
typedef __bf16 bf16x4 __attribute__((ext_vector_type(4)));
typedef float  f32x4  __attribute__((ext_vector_type(4)));

// ---- workspace layout (bytes) ----
#define WS_CURSORS 0         // 8 int
#define WS_NTILES  64        // 1 int
#define WS_FLAG    128       // 1 int (ids are int64?)
#define WS_TINFO   256       // MAXTILES*3 int
#define WS_PERM    4096      // 8192 int
#define WS_XA      0x10000   // 8192*64 bf16 (1 MB)
#define WS_ABF     0x110000  // 512*4096 bf16 (4 MB)
#define WS_BT      0x510000  // 4096*512 bf16 (4 MB)
#define WS_XAP     0x910000  // KSPLIT*8192*64 fp32 (8 MB)
#define WS_END     (0x910000 + (size_t)KSPLIT * T_TOK * RANK * 4)

__device__ __forceinline__ void gll16(const void* g, void* l) {
  __builtin_amdgcn_global_load_lds(
      (const __attribute__((address_space(1))) unsigned int*)g,
      (__attribute__((address_space(3))) unsigned int*)l, 16, 0, 0);
}

// ---------------- prep: histogram + offsets + tile table ----------------
__global__ __launch_bounds__(1024) void hist_prep(const int* __restrict__ ids,
    int* __restrict__ cursors, int* __restrict__ ntilesp,
    int* __restrict__ flagp, int* __restrict__ tinfo) {
  __shared__ int cnt[NAD];
  __shared__ int s_ofs[NAD], s_tbase[NAD + 1];
  __shared__ int s_is64;
  int tid = threadIdx.x, lane = tid & 63;
  if (tid < NAD) cnt[tid] = 0;
  if (tid == 0) s_is64 = 1;
  __syncthreads();
  // int64 detection: values are 0..7, so if data is i64 every odd 32-bit word is 0
  int any = 0;
  for (int i = tid; i < T_TOK; i += 1024)
    if (i & 1) any |= ids[i];
  if (any) s_is64 = 0;
  __syncthreads();
  int is64 = s_is64;
  int loc[NAD];
#pragma unroll
  for (int a = 0; a < NAD; ++a) loc[a] = 0;
  for (int t = tid; t < T_TOK; t += 1024) {
    int id = (is64 ? ids[2 * t] : ids[t]) & 7;
#pragma unroll
    for (int a = 0; a < NAD; ++a) {
      unsigned long long m = __ballot(id == a);
      if (lane == 0) loc[a] += __popcll(m);
    }
  }
  if (lane == 0) {
#pragma unroll
    for (int a = 0; a < NAD; ++a) if (loc[a]) atomicAdd(&cnt[a], loc[a]);
  }
  __syncthreads();
  if (tid == 0) {
    *flagp = is64;
    int ofs = 0, tb = 0;
    for (int a = 0; a < NAD; ++a) {
      s_ofs[a] = ofs; cursors[a] = ofs;
      s_tbase[a] = tb;
      ofs += cnt[a];
      tb += (cnt[a] + TS - 1) / TS;
    }
    s_tbase[NAD] = tb;
    *ntilesp = tb;
  }
  __syncthreads();
  int ntt = s_tbase[NAD];
  for (int e = tid; e < ntt; e += 1024) {
    int a = 0;
    while (e >= s_tbase[a + 1]) ++a;
    int t0 = (e - s_tbase[a]) * TS;
    int c = cnt[a];
    tinfo[e * 3 + 0] = a;
    tinfo[e * 3 + 1] = s_ofs[a] + t0;
    tinfo[e * 3 + 2] = (c - t0 < TS) ? (c - t0) : TS;
  }
}

// ---------------- scatter tokens into per-adapter groups (wave-aggregated atomics) ----------------
__global__ __launch_bounds__(256) void scatter_k(const int* __restrict__ ids,
    const int* __restrict__ flagp, int* __restrict__ cursors, int* __restrict__ perm) {
  int t = blockIdx.x * 256 + threadIdx.x;
  int lane = threadIdx.x & 63;
  int id = ((*flagp) ? ids[2 * t] : ids[t]) & 7;
  unsigned long long lt = (1ull << lane) - 1ull;
#pragma unroll
  for (int a = 0; a < NAD; ++a) {
    unsigned long long m = __ballot(id == a);
    if (m) {
      int leader = __ffsll((long long)m) - 1;
      int base_a = 0;
      if (lane == leader) base_a = atomicAdd(&cursors[a], __popcll(m));
      base_a = __shfl(base_a, leader, 64);
      if (id == a) perm[base_a + __popcll(m & lt)] = t;
    }
  }
}

// ---------------- A fp32 -> bf16 (row major) ----------------
__global__ __launch_bounds__(256) void conv_a(const float* __restrict__ A,
                                              __bf16* __restrict__ Abf) {
  int i = blockIdx.x * 256 + threadIdx.x;          // TOTR*DIN/4 elements
  float4 v = ((const float4*)A)[i];
  bf16x4 o = { (__bf16)v.x, (__bf16)v.y, (__bf16)v.z, (__bf16)v.w };
  ((bf16x4*)Abf)[i] = o;
}

// ---------------- B fp32 [512][4096] -> Bt bf16 [4096][512] ----------------
__global__ __launch_bounds__(256) void trans_b(const float* __restrict__ B,
                                               __bf16* __restrict__ Bt) {
  __shared__ float t[64][65];
  int rb = blockIdx.x, db = blockIdx.y;
  int tid = threadIdx.x;
  int c = tid & 63, q = tid >> 6;                  // q: 0..3
#pragma unroll
  for (int i = 0; i < 16; ++i) {
    int r = i * 4 + q;
    t[r][c] = B[(size_t)(rb * 64 + r) * DOUT + db * 64 + c];
  }
  __syncthreads();
#pragma unroll
  for (int i = 0; i < 16; ++i) {
    int d = i * 4 + q;
    Bt[(size_t)(db * 64 + d) * TOTR + rb * 64 + c] = (__bf16)t[c][d];
  }
}

#define CVT8(lo, hi) { (__bf16)lo.x, (__bf16)lo.y, (__bf16)lo.z, (__bf16)lo.w, \
                       (__bf16)hi.x, (__bf16)hi.y, (__bf16)hi.z, (__bf16)hi.w }

// ---------------- stage 1 (split-K, LDS-staged): xap[ks][tok][rank] = X * A_a^T ----------------
__global__ __launch_bounds__(512) void stage1s(const float* __restrict__ x,
    const __bf16* __restrict__ Abf, const int* __restrict__ tinfo,
    const int* __restrict__ ntilesp, const int* __restrict__ perm,
    float* __restrict__ xap) {
  __shared__ char lds[2][16384];   // per buf: [0,8192) = x tile, [8192,16384) = A tile
  int b = blockIdx.x;
  if (b >= *ntilesp) return;       // uniform
  int ks = blockIdx.y;
  int a = tinfo[b * 3], start = tinfo[b * 3 + 1], nv = tinfo[b * 3 + 2];
  int tid = threadIdx.x, lane = tid & 63, wv = tid >> 6;

  // ---- staging addresses (constant across K-steps) ----
  int xr = wv * 4 + (lane >> 4);                       // x row this lane stages
  int xtok = (xr < nv) ? perm[start + xr] : perm[start];
  int xinner = ((lane & 15) * 16) ^ ((xr & 7) << 4);   // swizzled source inner bytes
  const char* xsrc = (const char*)(x + (size_t)xtok * DIN + ks * KCH) + xinner;
  int ar = wv * 8 + (lane >> 3);                       // A row this lane stages
  int ainner = ((lane & 7) * 16) ^ ((ar & 7) << 4);
  const char* asrc = (const char*)(Abf + (size_t)(a * RANK + ar) * DIN + ks * KCH) + ainner;

  // ---- compute-side indices ----
  int l16 = lane & 15, lq = lane >> 4;
  int rb = wv & 1, cb = wv >> 1;
  int xrow = rb * 16 + l16;        // token row (MFMA A-operand)
  int arow = cb * 16 + l16;        // rank row  (MFMA B-operand)
  int swx = (xrow & 7) << 4;
  int swa = (arow & 7) << 4;

  f32x4 acc = {0.f, 0.f, 0.f, 0.f};

  // prologue: stage K-step 0 into buf 0
  gll16(xsrc, &lds[0][wv * 1024]);
  gll16(asrc, &lds[0][8192 + wv * 1024]);

  for (int t = 0; t < NT; ++t) {
    const char* cbuf = lds[t & 1];
    if (t + 1 < NT) {
      char* nbuf = lds[(t + 1) & 1];
      gll16(xsrc + (size_t)(t + 1) * 256, nbuf + wv * 1024);
      gll16(asrc + (size_t)(t + 1) * 128, nbuf + 8192 + wv * 1024);
      asm volatile("s_waitcnt vmcnt(2)" ::: "memory");   // cur's 2 loads landed (loads only in queue)
    } else {
      asm volatile("s_waitcnt vmcnt(0)" ::: "memory");
    }
    __builtin_amdgcn_s_barrier();
    asm volatile("" ::: "memory");
#pragma unroll
    for (int m = 0; m < 2; ++m) {
      f32x4 xv0 = *(const f32x4*)(cbuf + xrow * 256 + ((m * 128 + lq * 32) ^ swx));
      f32x4 xv1 = *(const f32x4*)(cbuf + xrow * 256 + ((m * 128 + lq * 32 + 16) ^ swx));
      bf16x8 xf = { (__bf16)xv0[0], (__bf16)xv0[1], (__bf16)xv0[2], (__bf16)xv0[3],
                    (__bf16)xv1[0], (__bf16)xv1[1], (__bf16)xv1[2], (__bf16)xv1[3] };
      bf16x8 af = *(const bf16x8*)(cbuf + 8192 + arow * 128 + ((m * 64 + lq * 16) ^ swa));
      acc = __builtin_amdgcn_mfma_f32_16x16x32_bf16(xf, af, acc, 0, 0, 0);
    }
    asm volatile("" ::: "memory");
    __builtin_amdgcn_s_barrier();
  }

  float* xo = xap + (size_t)ks * T_TOK * RANK;
#pragma unroll
  for (int j = 0; j < 4; ++j) {
    int tr = rb * 16 + lq * 4 + j;
    if (tr < nv) {
      int tk = perm[start + tr];
      xo[(size_t)tk * RANK + cb * 16 + l16] = acc[j];
    }
  }
}

// ---------------- reduce partials -> bf16 xa ----------------
__global__ __launch_bounds__(256) void reduce_xa(const float* __restrict__ xap,
                                                 __bf16* __restrict__ xa) {
  int i = blockIdx.x * 256 + threadIdx.x;          // 131072 float4 groups
  const float4* p = (const float4*)xap;
  float4 s = p[i];
#pragma unroll
  for (int ks = 1; ks < KSPLIT; ++ks) {
    float4 q = p[(size_t)ks * (T_TOK * RANK / 4) + i];
    s.x += q.x; s.y += q.y; s.z += q.z; s.w += q.w;
  }
  bf16x4 o = { (__bf16)s.x, (__bf16)s.y, (__bf16)s.z, (__bf16)s.w };
  ((bf16x4*)xa)[i] = o;
}

// ---------------- stage 1 fallback (no split-K) — used only if ws too small ----------------
__global__ __launch_bounds__(512) void stage1f(const float* __restrict__ x,
    const __bf16* __restrict__ Abf, const int* __restrict__ tinfo,
    const int* __restrict__ ntilesp, const int* __restrict__ perm,
    __bf16* __restrict__ xa) {
  int b = blockIdx.x;
  if (b >= *ntilesp) return;
  int a = tinfo[b * 3], start = tinfo[b * 3 + 1], nv = tinfo[b * 3 + 2];
  int tid = threadIdx.x, lane = tid & 63, w = tid >> 6;
  int rb = w & 1, cb = w >> 1;
  int l16 = lane & 15, lq = lane >> 4;
  int trow = rb * 16 + l16;
  int tok = (trow < nv) ? perm[start + trow] : 0;
  const float*  xrow = x + (size_t)tok * DIN + lq * 8;
  const __bf16* arow = Abf + (size_t)(a * RANK + cb * 16 + l16) * DIN + lq * 8;
  f32x4 acc = {0.f, 0.f, 0.f, 0.f};
#pragma unroll 4
  for (int k0 = 0; k0 < DIN; k0 += 32) {
    float4 v0 = *(const float4*)(xrow + k0);
    float4 v1 = *(const float4*)(xrow + k0 + 4);
    bf16x8 af = CVT8(v0, v1);
    bf16x8 bfr = *(const bf16x8*)(arow + k0);
    acc = __builtin_amdgcn_mfma_f32_16x16x32_bf16(af, bfr, acc, 0, 0, 0);
  }
#pragma unroll
  for (int j = 0; j < 4; ++j) {
    int tr = rb * 16 + lq * 4 + j;
    if (tr < nv) {
      int tk = perm[start + tr];
      xa[(size_t)tk * RANK + cb * 16 + l16] = (__bf16)acc[j];
    }
  }
}

// ---------------- stage 2 (LDS-staged, pipelined): out[32 tok][512 d] = base + 2 * xa * B_a ----
// grid (DSPLIT, MAXTILES), block 512 (8 waves). NS=8 steps of 64 d.
// Per step: stage base-tile [32tok][64d] f32 (8KB) + Bt-tile [64d][64r] bf16 (8KB) via
// global_load_lds, double-buffered, counted vmcnt(2) — the in-loop VMEM queue is PURE LOADS.
// Results accumulate in res[NS] registers (statically indexed, full unroll); all stores
// happen in an epilogue AFTER the loop. Rationale: loads and stores retire OUT OF ORDER
// relative to each other on CDNA, so counted-vmcnt arithmetic that includes a store is
// unsound (round-6 failure). Keeping stores out of the loop makes the counts exact AND
// removes store-retirement waits from the critical path.
__global__ __launch_bounds__(512) void stage2(const __bf16* __restrict__ xa,
    const __bf16* __restrict__ Bt, const float* __restrict__ base,
    const int* __restrict__ tinfo, const int* __restrict__ ntilesp,
    const int* __restrict__ perm, float* __restrict__ out) {
  __shared__ char lds[2][16384];   // per buf: [0,8192) = base tile, [8192,16384) = Bt tile
  int b = blockIdx.y;
  if (b >= *ntilesp) return;       // uniform
  int a = tinfo[b * 3], start = tinfo[b * 3 + 1], nv = tinfo[b * 3 + 2];
  int tid = threadIdx.x, lane = tid & 63, wv = tid >> 6;
  int dblk = blockIdx.x * DCH;

  // ---- staging addresses (advance by step) ----
  int brow = wv * 4 + (lane >> 4);                     // base-tile token row 0..31
  int btok = (brow < nv) ? perm[start + brow] : perm[start];
  int binner = ((lane & 15) * 16) ^ ((brow & 7) << 4);
  const char* bsrc = (const char*)(base + (size_t)btok * DOUT + dblk) + binner;
  int trow = wv * 8 + (lane >> 3);                     // Bt-tile d row 0..63
  int tinner = ((lane & 7) * 16) ^ ((trow & 7) << 4);
  const char* tsrc = (const char*)(Bt + (size_t)(dblk + trow) * TOTR + a * RANK) + tinner;

  // ---- compute mapping: wave -> token half (wv&1), 16-d slice (wv>>1) ----
  int tb = wv & 1, dg = wv >> 1;
  int l16 = lane & 15, lq = lane >> 4;
  int tIdx = tb * 16 + l16;        // token index in tile (C col)
  bool valid = tIdx < nv;
  int token = valid ? perm[start + tIdx] : perm[start];

  // xa fragments (B-operand), fixed for whole block
  const __bf16* xrow = xa + (size_t)token * RANK + lq * 8;
  bf16x8 xv0 = *(const bf16x8*)(xrow);
  bf16x8 xv1 = *(const bf16x8*)(xrow + 32);

  float* orow = out + (size_t)token * DOUT + dblk + dg * 16 + lq * 4;

  // LDS read offsets (per-step constant)
  int btrow = dg * 16 + l16;                           // d row in Bt tile
  int btoff0 = btrow * 128 + ((lq * 16) ^ ((btrow & 7) << 4));
  int btoff1 = btrow * 128 + ((lq * 16 + 64) ^ ((btrow & 7) << 4));
  int bsoff  = tIdx * 256 + ((dg * 64 + lq * 16) ^ ((tIdx & 7) << 4));

  f32x4 res[NS];                   // statically indexed under full unroll

  asm volatile("" ::: "memory");
  // prologue: stage step 0 into buf 0
  gll16(bsrc, &lds[0][wv * 1024]);
  gll16(tsrc, &lds[0][8192 + wv * 1024]);

#pragma unroll
  for (int t = 0; t < NS; ++t) {
    const char* cbuf = lds[t & 1];
    if (t + 1 < NS) {
      char* nbuf = lds[(t + 1) & 1];
      gll16(bsrc + (size_t)(t + 1) * 256,   nbuf + wv * 1024);          // +64 d = 256 B/row
      gll16(tsrc + (size_t)(t + 1) * 65536, nbuf + 8192 + wv * 1024);   // +64 rows * 1024 B
      // queue (pure loads): [s_t x2, s_{t+1} x2] -> wait the 2 oldest = current step
      asm volatile("s_waitcnt vmcnt(2)" ::: "memory");
    } else {
      asm volatile("s_waitcnt vmcnt(0)" ::: "memory");
    }
    __builtin_amdgcn_s_barrier();
    asm volatile("" ::: "memory");
    bf16x8 bf0 = *(const bf16x8*)(cbuf + 8192 + btoff0);
    bf16x8 bf1 = *(const bf16x8*)(cbuf + 8192 + btoff1);
    f32x4  bs  = *(const f32x4*)(cbuf + bsoff);
    f32x4 z = {0.f, 0.f, 0.f, 0.f};
    z = __builtin_amdgcn_mfma_f32_16x16x32_bf16(bf0, xv0, z, 0, 0, 0);
    z = __builtin_amdgcn_mfma_f32_16x16x32_bf16(bf1, xv1, z, 0, 0, 0);
    res[t][0] = bs[0] + 2.0f * z[0];
    res[t][1] = bs[1] + 2.0f * z[1];
    res[t][2] = bs[2] + 2.0f * z[2];
    res[t][3] = bs[3] + 2.0f * z[3];
    asm volatile("" ::: "memory");
    __builtin_amdgcn_s_barrier();
  }

  // epilogue: all stores issued here; nothing waits on them inside the loop
  if (valid) {
#pragma unroll
    for (int t = 0; t < NS; ++t)
      *(float4*)(orow + t * 64) = *(const float4*)&res[t];
  }
}

extern "C" void kernel_launch(void* const* d_in, const int* in_sizes, int n_in,
                              void* d_out, int out_size, void* d_ws, size_t ws_size,
                              hipStream_t stream) {
  const float* x   = (const float*)d_in[0];
  const float* A   = (const float*)d_in[1];
  const float* B   = (const float*)d_in[2];
  const float* bas = (const float*)d_in[3];
  const int*   ids = (const int*)d_in[4];
  float* out = (float*)d_out;
  char* ws = (char*)d_ws;
  int* cursors = (int*)(ws + WS_CURSORS);
  int* ntiles  = (int*)(ws + WS_NTILES);
  int* flag    = (int*)(ws + WS_FLAG);
  int* tinfo   = (int*)(ws + WS_TINFO);
  int* perm    = (int*)(ws + WS_PERM);
  __bf16* xa   = (__bf16*)(ws + WS_XA);
  __bf16* Abf  = (__bf16*)(ws + WS_ABF);
  __bf16* Bt   = (__bf16*)(ws + WS_BT);
  float*  xap  = (float*)(ws + WS_XAP);

  hist_prep<<<1, 1024, 0, stream>>>(ids, cursors, ntiles, flag, tinfo);
  scatter_k<<<T_TOK / 256, 256, 0, stream>>>(ids, flag, cursors, perm);
  conv_a<<<(TOTR * DIN / 4) / 256, 256, 0, stream>>>(A, Abf);
  trans_b<<<dim3(TOTR / 64, DOUT / 64), 256, 0, stream>>>(B, Bt);
  if (ws_size >= WS_END) {
    stage1s<<<dim3(MAXTILES, KSPLIT), 512, 0, stream>>>(x, Abf, tinfo, ntiles, perm, xap);
    reduce_xa<<<(T_TOK * RANK / 4) / 256, 256, 0, stream>>>(xap, xa);
  } else {
    stage1f<<<MAXTILES, 512, 0, stream>>>(x, Abf, tinfo, ntiles, perm, xa);
  }
  stage2<<<dim3(DSPLIT, MAXTILES), 512, 0, stream>>>(xa, Bt, bas, tinfo, ntiles, perm, out);
}